// Round 1
// baseline (355.457 us; speedup 1.0000x reference)
//
#include <hip/hip_runtime.h>
#include <hip/hip_bf16.h>

typedef __attribute__((ext_vector_type(4))) float f32x4;
typedef __attribute__((ext_vector_type(8))) short bf16x8;  // 8 bf16 bit-patterns (4 VGPRs)

#define M_DIM 8192
#define N_DIM 8192
#define K_DIM 2048
#define WCOUNT (N_DIM * K_DIM)   // 16,777,216 weight elements

// ---------------- kernel 1: per-block partial sums of |w| ----------------
__global__ __launch_bounds__(256) void k_abs_partial(const float* __restrict__ w,
                                                     float* __restrict__ part) {
    int tid = blockIdx.x * 256 + threadIdx.x;
    const float4* w4 = (const float4*)w;
    float s = 0.0f;
    const int total4 = WCOUNT / 4;
    for (int i = tid; i < total4; i += 2048 * 256) {
        float4 v = w4[i];
        s += fabsf(v.x) + fabsf(v.y) + fabsf(v.z) + fabsf(v.w);
    }
    #pragma unroll
    for (int off = 1; off < 64; off <<= 1) s += __shfl_xor(s, off);
    __shared__ float red[4];
    if ((threadIdx.x & 63) == 0) red[threadIdx.x >> 6] = s;
    __syncthreads();
    if (threadIdx.x == 0)
        part[blockIdx.x] = (red[0] + red[1]) + (red[2] + red[3]);
}

// ---------------- kernel 2: deterministic final reduce -> sum|w| ----------------
__global__ __launch_bounds__(256) void k_abs_final(const float* __restrict__ part,
                                                   float* __restrict__ sum) {
    int t = threadIdx.x;
    float s = 0.0f;
    #pragma unroll
    for (int i = 0; i < 8; i++) s += part[t + i * 256];
    #pragma unroll
    for (int off = 1; off < 64; off <<= 1) s += __shfl_xor(s, off);
    __shared__ float red[4];
    if ((t & 63) == 0) red[t >> 6] = s;
    __syncthreads();
    if (t == 0) sum[0] = (red[0] + red[1]) + (red[2] + red[3]);
}

// ---------------- kernel 3: ternary weight quant -> bf16 {-1,0,1} ----------------
__global__ __launch_bounds__(256) void k_wquant(const float* __restrict__ w,
                                                const float* __restrict__ sum,
                                                unsigned short* __restrict__ wq) {
    const float thr = 0.5f * (sum[0] * (1.0f / 16777216.0f));
    int tid = blockIdx.x * 256 + threadIdx.x;
    const float4* w4 = (const float4*)w;
    ushort4* q4 = (ushort4*)wq;
    const int total4 = WCOUNT / 4;
    for (int i = tid; i < total4; i += 2048 * 256) {
        float4 v = w4[i];
        ushort4 q;
        q.x = v.x > thr ? 0x3F80u : (v.x < -thr ? 0xBF80u : 0u);
        q.y = v.y > thr ? 0x3F80u : (v.y < -thr ? 0xBF80u : 0u);
        q.z = v.z > thr ? 0x3F80u : (v.z < -thr ? 0xBF80u : 0u);
        q.w = v.w > thr ? 0x3F80u : (v.w < -thr ? 0xBF80u : 0u);
        q4[i] = q;
    }
}

// ---------------- kernel 4: per-row activation quant -> bf16 ints + scale ----------------
__global__ __launch_bounds__(256) void k_xquant(const float* __restrict__ x,
                                                unsigned short* __restrict__ xq,
                                                float* __restrict__ scale) {
    const int row = blockIdx.x;
    const int t = threadIdx.x;
    const float4* xr = (const float4*)(x + (size_t)row * K_DIM);
    float4 a = xr[t * 2];
    float4 b = xr[t * 2 + 1];
    float m = fmaxf(fmaxf(fmaxf(fabsf(a.x), fabsf(a.y)), fmaxf(fabsf(a.z), fabsf(a.w))),
                    fmaxf(fmaxf(fabsf(b.x), fabsf(b.y)), fmaxf(fabsf(b.z), fabsf(b.w))));
    #pragma unroll
    for (int off = 1; off < 64; off <<= 1) m = fmaxf(m, __shfl_xor(m, off));
    __shared__ float red[4];
    if ((t & 63) == 0) red[t >> 6] = m;
    __syncthreads();
    m = fmaxf(fmaxf(red[0], red[1]), fmaxf(red[2], red[3]));
    const float sc = fmaxf(m, 1e-5f);
    if (t == 0) scale[row] = sc;
    const float r = 127.0f / sc;
    float q[8] = {a.x, a.y, a.z, a.w, b.x, b.y, b.z, b.w};
    union { unsigned short u[8]; uint4 v; } pk;
    #pragma unroll
    for (int j = 0; j < 8; j++) {
        float v = rintf(q[j] * r);                     // round-half-even, matches jnp.round
        v = fminf(fmaxf(v, -127.0f), 127.0f);
        pk.u[j] = (unsigned short)(__float_as_uint(v) >> 16);  // exact: small ints fit bf16
    }
    *(uint4*)(xq + (size_t)row * K_DIM + t * 8) = pk.v;
}

// ---------------- kernel 5: bf16 MFMA GEMM (m97 structure) + fused epilogue ----------------
// A = x_q [M][K] bf16, B = w_q [N][K] bf16 (B^T input), out[M][N] fp32 = relu(acc*coef)^2
#define GLDS16(g, l)                                                                   \
    __builtin_amdgcn_global_load_lds((const __attribute__((address_space(1))) void*)(g), \
                                     (__attribute__((address_space(3))) void*)(l), 16, 0, 0)

__global__ __launch_bounds__(256) void k_gemm(const unsigned short* __restrict__ Aq,
                                              const unsigned short* __restrict__ Bq,
                                              const float* __restrict__ scale,
                                              const float* __restrict__ sum,
                                              float* __restrict__ out) {
    __shared__ unsigned short As[128 * 32];  // 8 KB, row-major [128][32]
    __shared__ unsigned short Bs[128 * 32];  // 8 KB

    const int t = threadIdx.x;
    const int lane = t & 63;
    const int wid = t >> 6;
    const int wr = wid >> 1;      // wave row (0..1)
    const int wc = wid & 1;       // wave col (0..1)
    const int brow = blockIdx.y;
    const int bcol = blockIdx.x;

    // staging: chunk c (16B = 8 bf16) -> row c>>2, k-offset (c&3)*8; thread owns c=t and c=t+256
    const unsigned short* ga0 = Aq + (size_t)(brow * 128 + (t >> 2)) * K_DIM + (t & 3) * 8;
    const unsigned short* ga1 = Aq + (size_t)(brow * 128 + ((t + 256) >> 2)) * K_DIM + (t & 3) * 8;
    const unsigned short* gb0 = Bq + (size_t)(bcol * 128 + (t >> 2)) * K_DIM + (t & 3) * 8;
    const unsigned short* gb1 = Bq + (size_t)(bcol * 128 + ((t + 256) >> 2)) * K_DIM + (t & 3) * 8;
    // LDS dest: wave-uniform base + lane*16B (HW rule). chunk c lands at byte c*16.
    unsigned short* lA0 = As + wid * 512;
    unsigned short* lA1 = As + 2048 + wid * 512;
    unsigned short* lB0 = Bs + wid * 512;
    unsigned short* lB1 = Bs + 2048 + wid * 512;

    f32x4 zero = {0.0f, 0.0f, 0.0f, 0.0f};
    f32x4 acc[4][4];
    #pragma unroll
    for (int m = 0; m < 4; m++)
        #pragma unroll
        for (int n = 0; n < 4; n++) acc[m][n] = zero;

    // fragment read offsets (elements): row r -> r*32 + (lane>>4)*8
    const int a_off = (wr * 64 + (lane & 15)) * 32 + (lane >> 4) * 8;
    const int b_off = (wc * 64 + (lane & 15)) * 32 + (lane >> 4) * 8;

    for (int kt = 0; kt < K_DIM; kt += 32) {
        GLDS16(ga0, lA0);
        GLDS16(ga1, lA1);
        GLDS16(gb0, lB0);
        GLDS16(gb1, lB1);
        ga0 += 32; ga1 += 32; gb0 += 32; gb1 += 32;
        __syncthreads();  // compiler emits vmcnt(0) drain before barrier

        bf16x8 af[4], bfr[4];
        #pragma unroll
        for (int m = 0; m < 4; m++) af[m] = *(const bf16x8*)&As[a_off + m * 512];
        #pragma unroll
        for (int n = 0; n < 4; n++) bfr[n] = *(const bf16x8*)&Bs[b_off + n * 512];
        #pragma unroll
        for (int m = 0; m < 4; m++)
            #pragma unroll
            for (int n = 0; n < 4; n++)
                acc[m][n] = __builtin_amdgcn_mfma_f32_16x16x32_bf16(af[m], bfr[n], acc[m][n], 0, 0, 0);
        __syncthreads();
    }

    // epilogue: out = (max(acc * w_scale / scale_row, 0))^2
    const float wsc = sum[0] * (1.0f / 16777216.0f);
    const int rbase = brow * 128 + wr * 64 + ((lane >> 4) * 4);
    const int cbase = bcol * 128 + wc * 64 + (lane & 15);
    #pragma unroll
    for (int m = 0; m < 4; m++) {
        #pragma unroll
        for (int j = 0; j < 4; j++) {
            const int grow = rbase + m * 16 + j;
            const float coef = wsc / scale[grow];
            #pragma unroll
            for (int n = 0; n < 4; n++) {
                float v = acc[m][n][j] * coef;   // C/D: col=lane&15, row=(lane>>4)*4+j
                v = fmaxf(v, 0.0f);
                out[(size_t)grow * N_DIM + cbase + n * 16] = v * v;
            }
        }
    }
}

// ---------------- launch ----------------
extern "C" void kernel_launch(void* const* d_in, const int* in_sizes, int n_in,
                              void* d_out, int out_size, void* d_ws, size_t ws_size,
                              hipStream_t stream) {
    const float* x = (const float*)d_in[0];   // [4,2048,2048] fp32
    const float* w = (const float*)d_in[1];   // [8192,2048] fp32
    // d_in[2] = bits (=8), folded into constants (max_val=127)
    float* out = (float*)d_out;               // [4,2048,8192] fp32

    char* ws = (char*)d_ws;
    float* sum   = (float*)ws;                 // 1 float
    float* part  = (float*)(ws + 256);         // 2048 floats
    float* scale = (float*)(ws + 16384);       // 8192 floats
    unsigned short* xq = (unsigned short*)(ws + 65536);              // 33.55 MB bf16
    unsigned short* wq = (unsigned short*)(ws + 65536 + 33554432);   // 33.55 MB bf16

    k_abs_partial<<<2048, 256, 0, stream>>>(w, part);
    k_abs_final<<<1, 256, 0, stream>>>(part, sum);
    k_wquant<<<2048, 256, 0, stream>>>(w, sum, wq);
    k_xquant<<<M_DIM, 256, 0, stream>>>(x, xq, scale);
    k_gemm<<<dim3(N_DIM / 128, M_DIM / 128), 256, 0, stream>>>(xq, wq, scale, sum, out);
}

// Round 2
// 223.685 us; speedup vs baseline: 1.5891x; 1.5891x over previous
//
#include <hip/hip_runtime.h>
#include <hip/hip_bf16.h>

typedef __attribute__((ext_vector_type(4))) int i32x4;

#define M_DIM 8192
#define N_DIM 8192
#define K_DIM 2048
#define WCOUNT (N_DIM * K_DIM)   // 16,777,216 weight elements

// ---------------- kernel 1: per-block partial sums of |w| ----------------
__global__ __launch_bounds__(256) void k_abs_partial(const float* __restrict__ w,
                                                     float* __restrict__ part) {
    int tid = blockIdx.x * 256 + threadIdx.x;
    const float4* w4 = (const float4*)w;
    float s = 0.0f;
    const int total4 = WCOUNT / 4;
    for (int i = tid; i < total4; i += 2048 * 256) {
        float4 v = w4[i];
        s += fabsf(v.x) + fabsf(v.y) + fabsf(v.z) + fabsf(v.w);
    }
    #pragma unroll
    for (int off = 1; off < 64; off <<= 1) s += __shfl_xor(s, off);
    __shared__ float red[4];
    if ((threadIdx.x & 63) == 0) red[threadIdx.x >> 6] = s;
    __syncthreads();
    if (threadIdx.x == 0)
        part[blockIdx.x] = (red[0] + red[1]) + (red[2] + red[3]);
}

// ---------------- kernel 2: deterministic final reduce -> sum|w| ----------------
__global__ __launch_bounds__(256) void k_abs_final(const float* __restrict__ part,
                                                   float* __restrict__ sum) {
    int t = threadIdx.x;
    float s = 0.0f;
    #pragma unroll
    for (int i = 0; i < 8; i++) s += part[t + i * 256];
    #pragma unroll
    for (int off = 1; off < 64; off <<= 1) s += __shfl_xor(s, off);
    __shared__ float red[4];
    if ((t & 63) == 0) red[t >> 6] = s;
    __syncthreads();
    if (t == 0) sum[0] = (red[0] + red[1]) + (red[2] + red[3]);
}

// ---------------- kernel 3: ternary weight quant -> int8 {-1,0,1} ----------------
__global__ __launch_bounds__(256) void k_wquant(const float* __restrict__ w,
                                                const float* __restrict__ sum,
                                                unsigned int* __restrict__ wq) {
    const float thr = 0.5f * (sum[0] * (1.0f / 16777216.0f));
    int tid = blockIdx.x * 256 + threadIdx.x;
    const float4* w4 = (const float4*)w;
    const int total4 = WCOUNT / 4;
    for (int i = tid; i < total4; i += 2048 * 256) {
        float4 v = w4[i];
        union { signed char c[4]; unsigned int u; } q;
        q.c[0] = v.x > thr ? 1 : (v.x < -thr ? -1 : 0);
        q.c[1] = v.y > thr ? 1 : (v.y < -thr ? -1 : 0);
        q.c[2] = v.z > thr ? 1 : (v.z < -thr ? -1 : 0);
        q.c[3] = v.w > thr ? 1 : (v.w < -thr ? -1 : 0);
        wq[i] = q.u;
    }
}

// ---------------- kernel 4: per-row activation quant -> int8 + scale ----------------
__global__ __launch_bounds__(256) void k_xquant(const float* __restrict__ x,
                                                signed char* __restrict__ xq,
                                                float* __restrict__ scale) {
    const int row = blockIdx.x;
    const int t = threadIdx.x;
    const float4* xr = (const float4*)(x + (size_t)row * K_DIM);
    float4 a = xr[t * 2];
    float4 b = xr[t * 2 + 1];
    float m = fmaxf(fmaxf(fmaxf(fabsf(a.x), fabsf(a.y)), fmaxf(fabsf(a.z), fabsf(a.w))),
                    fmaxf(fmaxf(fabsf(b.x), fabsf(b.y)), fmaxf(fabsf(b.z), fabsf(b.w))));
    #pragma unroll
    for (int off = 1; off < 64; off <<= 1) m = fmaxf(m, __shfl_xor(m, off));
    __shared__ float red[4];
    if ((t & 63) == 0) red[t >> 6] = m;
    __syncthreads();
    m = fmaxf(fmaxf(red[0], red[1]), fmaxf(red[2], red[3]));
    const float sc = fmaxf(m, 1e-5f);
    if (t == 0) scale[row] = sc;
    const float r = 127.0f / sc;
    float q[8] = {a.x, a.y, a.z, a.w, b.x, b.y, b.z, b.w};
    union { signed char c[8]; uint2 v; } pk;
    #pragma unroll
    for (int j = 0; j < 8; j++) {
        float v = rintf(q[j] * r);                     // round-half-even, matches jnp.round
        v = fminf(fmaxf(v, -127.0f), 127.0f);
        pk.c[j] = (signed char)v;
    }
    *(uint2*)(xq + (size_t)row * K_DIM + t * 8) = pk.v;
}

// ---------------- kernel 5: i8 MFMA GEMM (m97 structure, swizzled LDS) ----------------
// A = x_q [M][K] i8, B = w_q [N][K] i8 (B^T input), out[M][N] fp32 = relu(acc*coef)^2
// LDS tile [128][64] bytes per matrix. Swizzle: 16B slot s at row r holds global
// chunk g = s ^ ((r>>1)&3). Linear global_load_lds dest + inverse-swizzled global
// source + swizzled ds_read (rule 21, both-sides-or-neither).
#define GLDS16(g, l)                                                                   \
    __builtin_amdgcn_global_load_lds((const __attribute__((address_space(1))) void*)(g), \
                                     (__attribute__((address_space(3))) void*)(l), 16, 0, 0)

__global__ __launch_bounds__(256) void k_gemm(const signed char* __restrict__ Aq,
                                              const signed char* __restrict__ Bq,
                                              const float* __restrict__ scale,
                                              const float* __restrict__ sum,
                                              float* __restrict__ out) {
    __shared__ signed char As[128 * 64];  // 8 KB
    __shared__ signed char Bs[128 * 64];  // 8 KB

    const int t = threadIdx.x;
    const int lane = t & 63;
    const int wid = t >> 6;
    const int wr = wid >> 1;      // wave row (0..1)
    const int wc = wid & 1;       // wave col (0..1)
    const int brow = blockIdx.y;
    const int bcol = blockIdx.x;

    // staging: chunk c (16B) -> LDS byte c*16 (linear). row(c)=c>>2, slot(c)=c&3.
    // slot s of row r must hold global chunk g = s ^ ((r>>1)&3) = (c&3) ^ ((c>>3)&3).
    const int c0 = t, c1 = t + 256;
    const int g0 = ((c0 & 3) ^ ((c0 >> 3) & 3)) * 16;
    const int g1 = ((c1 & 3) ^ ((c1 >> 3) & 3)) * 16;
    const signed char* ga0 = Aq + (size_t)(brow * 128 + (c0 >> 2)) * K_DIM + g0;
    const signed char* ga1 = Aq + (size_t)(brow * 128 + (c1 >> 2)) * K_DIM + g1;
    const signed char* gb0 = Bq + (size_t)(bcol * 128 + (c0 >> 2)) * K_DIM + g0;
    const signed char* gb1 = Bq + (size_t)(bcol * 128 + (c1 >> 2)) * K_DIM + g1;
    // LDS dest: wave-uniform base + lane*16B. chunk c lands at byte c*16.
    signed char* lA0 = As + wid * 1024;
    signed char* lA1 = As + 4096 + wid * 1024;
    signed char* lB0 = Bs + wid * 1024;
    signed char* lB1 = Bs + 4096 + wid * 1024;

    i32x4 zero = {0, 0, 0, 0};
    i32x4 acc[4][4];
    #pragma unroll
    for (int m = 0; m < 4; m++)
        #pragma unroll
        for (int n = 0; n < 4; n++) acc[m][n] = zero;

    // fragment read (bytes): row = base + m*16 + (lane&15); k-slot = lane>>4,
    // swizzled slot = (lane>>4) ^ ((row>>1)&3); ((row>>1)&3) == ((lane>>1)&3) since
    // base and m*16 are multiples of 16.
    const int swz = ((lane >> 4) ^ ((lane >> 1) & 3)) * 16;
    const int a_off = (wr * 64 + (lane & 15)) * 64 + swz;
    const int b_off = (wc * 64 + (lane & 15)) * 64 + swz;

    for (int kt = 0; kt < K_DIM; kt += 64) {
        GLDS16(ga0, lA0);
        GLDS16(ga1, lA1);
        GLDS16(gb0, lB0);
        GLDS16(gb1, lB1);
        ga0 += 64; ga1 += 64; gb0 += 64; gb1 += 64;
        __syncthreads();

        i32x4 af[4], bfr[4];
        #pragma unroll
        for (int m = 0; m < 4; m++) af[m] = *(const i32x4*)&As[a_off + m * 1024];
        #pragma unroll
        for (int n = 0; n < 4; n++) bfr[n] = *(const i32x4*)&Bs[b_off + n * 1024];
        #pragma unroll
        for (int m = 0; m < 4; m++)
            #pragma unroll
            for (int n = 0; n < 4; n++)
                acc[m][n] = __builtin_amdgcn_mfma_i32_16x16x64_i8(af[m], bfr[n], acc[m][n], 0, 0, 0);
        __syncthreads();
    }

    // epilogue: out = (max(acc * w_scale / scale_row, 0))^2
    const float wsc = sum[0] * (1.0f / 16777216.0f);
    const int rbase = brow * 128 + wr * 64 + ((lane >> 4) * 4);
    const int cbase = bcol * 128 + wc * 64 + (lane & 15);
    #pragma unroll
    for (int m = 0; m < 4; m++) {
        #pragma unroll
        for (int j = 0; j < 4; j++) {
            const int grow = rbase + m * 16 + j;
            const float coef = wsc / scale[grow];
            #pragma unroll
            for (int n = 0; n < 4; n++) {
                float v = (float)acc[m][n][j] * coef;   // C/D: col=lane&15, row=(lane>>4)*4+j
                v = fmaxf(v, 0.0f);
                out[(size_t)grow * N_DIM + cbase + n * 16] = v * v;
            }
        }
    }
}

// ---------------- launch ----------------
extern "C" void kernel_launch(void* const* d_in, const int* in_sizes, int n_in,
                              void* d_out, int out_size, void* d_ws, size_t ws_size,
                              hipStream_t stream) {
    const float* x = (const float*)d_in[0];   // [4,2048,2048] fp32
    const float* w = (const float*)d_in[1];   // [8192,2048] fp32
    // d_in[2] = bits (=8), folded into constants (max_val=127)
    float* out = (float*)d_out;               // [4,2048,8192] fp32

    char* ws = (char*)d_ws;
    float* sum   = (float*)ws;                 // 1 float
    float* part  = (float*)(ws + 256);         // 2048 floats
    float* scale = (float*)(ws + 16384);       // 8192 floats
    signed char* xq = (signed char*)(ws + 65536);              // 16.78 MB i8
    signed char* wq = (signed char*)(ws + 65536 + 16777216);   // 16.78 MB i8

    k_abs_partial<<<2048, 256, 0, stream>>>(w, part);
    k_abs_final<<<1, 256, 0, stream>>>(part, sum);
    k_wquant<<<2048, 256, 0, stream>>>(w, sum, (unsigned int*)wq);
    k_xquant<<<M_DIM, 256, 0, stream>>>(x, xq, scale);
    k_gemm<<<dim3(N_DIM / 128, M_DIM / 128), 256, 0, stream>>>(xq, wq, scale, sum, out);
}

// Round 3
// 202.043 us; speedup vs baseline: 1.7593x; 1.1071x over previous
//
#include <hip/hip_runtime.h>
#include <hip/hip_bf16.h>

typedef __attribute__((ext_vector_type(4))) int i32x4;

#define M_DIM 8192
#define N_DIM 8192
#define K_DIM 2048
#define BK 128                   // i8 K-bytes per K-tile
#define WCOUNT (N_DIM * K_DIM)   // 16,777,216 weight elements

// ---------------- kernel 1: per-block partial sums of |w| ----------------
__global__ __launch_bounds__(256) void k_abs_partial(const float* __restrict__ w,
                                                     float* __restrict__ part) {
    int tid = blockIdx.x * 256 + threadIdx.x;
    const float4* w4 = (const float4*)w;
    float s = 0.0f;
    const int total4 = WCOUNT / 4;
    for (int i = tid; i < total4; i += 2048 * 256) {
        float4 v = w4[i];
        s += fabsf(v.x) + fabsf(v.y) + fabsf(v.z) + fabsf(v.w);
    }
    #pragma unroll
    for (int off = 1; off < 64; off <<= 1) s += __shfl_xor(s, off);
    __shared__ float red[4];
    if ((threadIdx.x & 63) == 0) red[threadIdx.x >> 6] = s;
    __syncthreads();
    if (threadIdx.x == 0)
        part[blockIdx.x] = (red[0] + red[1]) + (red[2] + red[3]);
}

// ---------------- kernel 2: deterministic final reduce -> sum|w| ----------------
__global__ __launch_bounds__(256) void k_abs_final(const float* __restrict__ part,
                                                   float* __restrict__ sum) {
    int t = threadIdx.x;
    float s = 0.0f;
    #pragma unroll
    for (int i = 0; i < 8; i++) s += part[t + i * 256];
    #pragma unroll
    for (int off = 1; off < 64; off <<= 1) s += __shfl_xor(s, off);
    __shared__ float red[4];
    if ((t & 63) == 0) red[t >> 6] = s;
    __syncthreads();
    if (t == 0) sum[0] = (red[0] + red[1]) + (red[2] + red[3]);
}

// ---------------- kernel 3: ternary weight quant -> int8 {-1,0,1} ----------------
__global__ __launch_bounds__(256) void k_wquant(const float* __restrict__ w,
                                                const float* __restrict__ sum,
                                                unsigned int* __restrict__ wq) {
    const float thr = 0.5f * (sum[0] * (1.0f / 16777216.0f));
    int tid = blockIdx.x * 256 + threadIdx.x;
    const float4* w4 = (const float4*)w;
    const int total4 = WCOUNT / 4;
    for (int i = tid; i < total4; i += 2048 * 256) {
        float4 v = w4[i];
        union { signed char c[4]; unsigned int u; } q;
        q.c[0] = v.x > thr ? 1 : (v.x < -thr ? -1 : 0);
        q.c[1] = v.y > thr ? 1 : (v.y < -thr ? -1 : 0);
        q.c[2] = v.z > thr ? 1 : (v.z < -thr ? -1 : 0);
        q.c[3] = v.w > thr ? 1 : (v.w < -thr ? -1 : 0);
        wq[i] = q.u;
    }
}

// ---------------- kernel 4: per-row activation quant -> int8 + scale ----------------
__global__ __launch_bounds__(256) void k_xquant(const float* __restrict__ x,
                                                signed char* __restrict__ xq,
                                                float* __restrict__ scale) {
    const int row = blockIdx.x;
    const int t = threadIdx.x;
    const float4* xr = (const float4*)(x + (size_t)row * K_DIM);
    float4 a = xr[t * 2];
    float4 b = xr[t * 2 + 1];
    float m = fmaxf(fmaxf(fmaxf(fabsf(a.x), fabsf(a.y)), fmaxf(fabsf(a.z), fabsf(a.w))),
                    fmaxf(fmaxf(fabsf(b.x), fabsf(b.y)), fmaxf(fabsf(b.z), fabsf(b.w))));
    #pragma unroll
    for (int off = 1; off < 64; off <<= 1) m = fmaxf(m, __shfl_xor(m, off));
    __shared__ float red[4];
    if ((t & 63) == 0) red[t >> 6] = m;
    __syncthreads();
    m = fmaxf(fmaxf(red[0], red[1]), fmaxf(red[2], red[3]));
    const float sc = fmaxf(m, 1e-5f);
    if (t == 0) scale[row] = sc;
    const float r = 127.0f / sc;
    float q[8] = {a.x, a.y, a.z, a.w, b.x, b.y, b.z, b.w};
    union { signed char c[8]; uint2 v; } pk;
    #pragma unroll
    for (int j = 0; j < 8; j++) {
        float v = rintf(q[j] * r);
        v = fminf(fmaxf(v, -127.0f), 127.0f);
        pk.c[j] = (signed char)v;
    }
    *(uint2*)(xq + (size_t)row * K_DIM + t * 8) = pk.v;
}

// ---------------- kernel 5: 256x256 8-phase i8 MFMA GEMM ----------------
// A = x_q [M][K] i8, B = w_q [N][K] i8, out[M][N] fp32 = relu(acc*coef)^2.
// 512 thr / 8 waves (2Mx4N). LDS 128 KiB = 2 K-tile buffers x (A 32K + B 32K),
// each matrix buffer = 2 half-tiles of 128 rows x 128 B. Swizzle: 16B slot s of
// row r holds global k-chunk g = s ^ ((r>>1)&7) (involution; source-side +
// read-side, LDS linear for global_load_lds).
// Schedule per iter (K-tiles 2i in buf0, 2i+1 in buf1):
//  ph1: [i>=1: stage B(kt2i+1)] read A03,B01(buf0) MFMA(m0-3,n0-1) BAR
//  ph2: read A47,B23(buf0) MFMA(m0-3,n2-3) BAR
//  ph3: MFMA(m4-7,n0-1) BAR
//  ph4: [i<=6: stage A(kt2i+2)] MFMA(m4-7,n2-3) vmcnt(4|0) BAR
//  ph5-8: mirror on buf1; ph5 stages B(kt2i+2), ph8 stages A(kt2i+3), vmcnt(4|0).
// Ledger: each buffer's reads are MFMA-forced complete >=1 barrier before its
// restage issue; each staged half-tile is vmcnt-gated >=1 barrier before reads.
#define GLDS16(g, l)                                                                   \
    __builtin_amdgcn_global_load_lds((const __attribute__((address_space(1))) void*)(g), \
                                     (__attribute__((address_space(3))) void*)(l), 16, 0, 0)

#define AOFF(b, h) ((b) * 32768 + (h) * 16384)
#define BOFF(b, h) (65536 + (b) * 32768 + (h) * 16384)
#define BAR __builtin_amdgcn_s_barrier()
#define VMCNT4 do { asm volatile("s_waitcnt vmcnt(4)" ::: "memory"); __builtin_amdgcn_sched_barrier(0); } while (0)
#define VMCNT0 do { asm volatile("s_waitcnt vmcnt(0)" ::: "memory"); __builtin_amdgcn_sched_barrier(0); } while (0)

__global__ __launch_bounds__(512, 2) void k_gemm(const signed char* __restrict__ Aq,
                                                 const signed char* __restrict__ Bq,
                                                 const float* __restrict__ scale,
                                                 const float* __restrict__ sum,
                                                 float* __restrict__ out) {
    __shared__ signed char lds[131072];

    const int t = threadIdx.x;
    const int lane = t & 63;
    const int wid = t >> 6;        // 0..7
    const int wm = wid >> 2;       // 0..1  (M half)
    const int wn = wid & 3;        // 0..3  (N quarter)
    const int lane4 = lane & 15;
    const int hi = lane >> 4;

    // XCD-aware swizzle (nwg=1024, %8==0): contiguous swz per XCD, N-major 2D map
    const int bid = blockIdx.x;
    const int swzb = ((bid & 7) << 7) | (bid >> 3);
    const int brow = swzb >> 5;
    const int bcol = swzb & 31;

    // ---- staging geometry: thread t owns chunks c0=t (rows 0..63) and c1=t+512
    // (rows 64..127) of each 128-row half-tile; src k-chunk inverse-swizzled.
    const int r0 = t >> 3;
    const int r1 = 64 + r0;
    const int g0 = ((t & 7) ^ ((t >> 4) & 7)) << 4;
    const int g1 = (((t + 512) & 7) ^ (((t + 512) >> 4) & 7)) << 4;
    const int sa0 = r0 * K_DIM + g0;     // + half*128*K_DIM + kt*BK
    const int sa1 = r1 * K_DIM + g1;
    const int dst0 = wid * 1024;         // + lane*16 implicit (wave-uniform base)
    const int dst1 = wid * 1024 + 8192;

    const signed char* Abase = Aq + (size_t)(brow * 256) * K_DIM;
    const signed char* Bbase = Bq + (size_t)(bcol * 256) * K_DIM;

#define STG(gb, ldsoff, half, kt) do {                                                  \
        GLDS16((gb) + (half) * (128 * K_DIM) + (kt) * BK + sa0, lds + (ldsoff) + dst0); \
        GLDS16((gb) + (half) * (128 * K_DIM) + (kt) * BK + sa1, lds + (ldsoff) + dst1); \
    } while (0)

    // ---- fragment read bases: row = m*16+lane4 (A) / (wn&1)*64+n*16+lane4 (B);
    // swizzled slot = (ks*4+hi) ^ (lane4>>1)  (lane-only, fragment-invariant)
    const int swz0 = (hi ^ (lane4 >> 1)) << 4;
    const int swz1 = ((4 + hi) ^ (lane4 >> 1)) << 4;
    const int aB0 = AOFF(0, wm) + lane4 * 128;
    const int aB1 = AOFF(1, wm) + lane4 * 128;
    const int bB0 = BOFF(0, wn >> 1) + ((wn & 1) * 64 + lane4) * 128;
    const int bB1 = BOFF(1, wn >> 1) + ((wn & 1) * 64 + lane4) * 128;

    i32x4 acc[8][4];
    #pragma unroll
    for (int m = 0; m < 8; m++)
        #pragma unroll
        for (int n = 0; n < 4; n++) acc[m][n] = (i32x4){0, 0, 0, 0};
    i32x4 fa0[8], fa1[8], fb0[4], fb1[4];

#define RDA(base, mlo) do { _Pragma("unroll") for (int m_ = 0; m_ < 4; m_++) {          \
        fa0[(mlo) + m_] = *(const i32x4*)&lds[(base) + ((mlo) + m_) * 2048 + swz0];     \
        fa1[(mlo) + m_] = *(const i32x4*)&lds[(base) + ((mlo) + m_) * 2048 + swz1]; } } while (0)
#define RDB(base, nlo) do { _Pragma("unroll") for (int n_ = 0; n_ < 2; n_++) {          \
        fb0[(nlo) + n_] = *(const i32x4*)&lds[(base) + ((nlo) + n_) * 2048 + swz0];     \
        fb1[(nlo) + n_] = *(const i32x4*)&lds[(base) + ((nlo) + n_) * 2048 + swz1]; } } while (0)
#define MM(mlo, nlo) do { __builtin_amdgcn_s_setprio(1);                                \
        _Pragma("unroll") for (int m_ = 0; m_ < 4; m_++)                                \
        _Pragma("unroll") for (int n_ = 0; n_ < 2; n_++) {                              \
            acc[(mlo) + m_][(nlo) + n_] = __builtin_amdgcn_mfma_i32_16x16x64_i8(        \
                fa0[(mlo) + m_], fb0[(nlo) + n_], acc[(mlo) + m_][(nlo) + n_], 0, 0, 0);\
            acc[(mlo) + m_][(nlo) + n_] = __builtin_amdgcn_mfma_i32_16x16x64_i8(        \
                fa1[(mlo) + m_], fb1[(nlo) + n_], acc[(mlo) + m_][(nlo) + n_], 0, 0, 0);\
        } __builtin_amdgcn_s_setprio(0); } while (0)

    // ---- prologue: kt0 -> buf0, kt1 -> buf1 (16 loads); wait kt0, kt1 in flight
    STG(Abase, AOFF(0, 0), 0, 0); STG(Abase, AOFF(0, 1), 1, 0);
    STG(Bbase, BOFF(0, 0), 0, 0); STG(Bbase, BOFF(0, 1), 1, 0);
    STG(Abase, AOFF(1, 0), 0, 1); STG(Abase, AOFF(1, 1), 1, 1);
    STG(Bbase, BOFF(1, 0), 0, 1); STG(Bbase, BOFF(1, 1), 1, 1);
    asm volatile("s_waitcnt vmcnt(8)" ::: "memory");
    __builtin_amdgcn_sched_barrier(0);
    BAR;

    #pragma unroll 1
    for (int i = 0; i < 8; i++) {
        const int kt = 2 * i;
        // ph1
        if (i >= 1) { STG(Bbase, BOFF(1, 0), 0, kt + 1); STG(Bbase, BOFF(1, 1), 1, kt + 1); }
        RDA(aB0, 0); RDB(bB0, 0);
        MM(0, 0);
        BAR;
        // ph2
        RDA(aB0, 4); RDB(bB0, 2);
        MM(0, 2);
        BAR;
        // ph3
        MM(4, 0);
        BAR;
        // ph4
        if (i <= 6) { STG(Abase, AOFF(0, 0), 0, kt + 2); STG(Abase, AOFF(0, 1), 1, kt + 2); }
        MM(4, 2);
        if (i <= 6) VMCNT4; else VMCNT0;
        BAR;
        // ph5
        if (i <= 6) { STG(Bbase, BOFF(0, 0), 0, kt + 2); STG(Bbase, BOFF(0, 1), 1, kt + 2); }
        RDA(aB1, 0); RDB(bB1, 0);
        MM(0, 0);
        BAR;
        // ph6
        RDA(aB1, 4); RDB(bB1, 2);
        MM(0, 2);
        BAR;
        // ph7
        MM(4, 0);
        BAR;
        // ph8
        if (i <= 6) { STG(Abase, AOFF(1, 0), 0, kt + 3); STG(Abase, AOFF(1, 1), 1, kt + 3); }
        MM(4, 2);
        if (i <= 6) VMCNT4; else VMCNT0;
        BAR;
    }

    // ---- epilogue: out = (max(acc * w_scale / scale_row, 0))^2
    const float wsc = sum[0] * (1.0f / 16777216.0f);
    const int rb = brow * 256 + wm * 128 + hi * 4;
    const int cb = bcol * 256 + wn * 64 + lane4;
    #pragma unroll
    for (int m = 0; m < 8; m++) {
        #pragma unroll
        for (int j = 0; j < 4; j++) {
            const int grow = rb + m * 16 + j;
            const float coef = wsc / scale[grow];
            #pragma unroll
            for (int n = 0; n < 4; n++) {
                float v = (float)acc[m][n][j] * coef;   // C/D: col=lane&15, row=hi*4+j
                v = fmaxf(v, 0.0f);
                out[(size_t)grow * N_DIM + cb + n * 16] = v * v;
            }
        }
    }
#undef STG
#undef RDA
#undef RDB
#undef MM
}

// ---------------- launch ----------------
extern "C" void kernel_launch(void* const* d_in, const int* in_sizes, int n_in,
                              void* d_out, int out_size, void* d_ws, size_t ws_size,
                              hipStream_t stream) {
    const float* x = (const float*)d_in[0];   // [4,2048,2048] fp32
    const float* w = (const float*)d_in[1];   // [8192,2048] fp32
    float* out = (float*)d_out;               // [4,2048,8192] fp32

    char* ws = (char*)d_ws;
    float* sum   = (float*)ws;                 // 1 float
    float* part  = (float*)(ws + 256);         // 2048 floats
    float* scale = (float*)(ws + 16384);       // 8192 floats
    signed char* xq = (signed char*)(ws + 65536);              // 16.78 MB i8
    signed char* wq = (signed char*)(ws + 65536 + 16777216);   // 16.78 MB i8

    k_abs_partial<<<2048, 256, 0, stream>>>(w, part);
    k_abs_final<<<1, 256, 0, stream>>>(part, sum);
    k_wquant<<<2048, 256, 0, stream>>>(w, sum, (unsigned int*)wq);
    k_xquant<<<M_DIM, 256, 0, stream>>>(x, xq, scale);
    k_gemm<<<dim3(1024), 512, 0, stream>>>(xq, wq, scale, sum, out);
}